// Round 5
// baseline (13130.109 us; speedup 1.0000x reference)
//
#include <hip/hip_runtime.h>
#include <stdint.h>

typedef unsigned long long ull;
typedef unsigned int uint;
typedef unsigned short ushort;

#define NPTS 4096
#define NC   256
#define M2C  512
#define NS   16
#define SLOPE 0.1f
#define GEPS 1e-5f

typedef __attribute__((ext_vector_type(8))) short short8;
typedef __attribute__((ext_vector_type(4))) float f32x4;

// ---- workspace layout (float units) ----
// NOTE (R5 fix): CB (combined bias) previously aliased sh2 (O_SS+1792 vs sh2@O_SS+1536..2047);
// gn2 finalize clobbered it after itx=0 -> itx>=1 built x0 with garbage bias (absmax 0.42).
// CB now has its own slot O_CB.
static const size_t O_NTF  = 0;                       // fp32 normalized knn, transposed [4][4096][256]
static const size_t O_NTB  = O_NTF  + 4194304;        // bf16 same
static const size_t O_FTBH = O_NTB  + 2097152;        // bf16 feat transposed hi [4][4096][256]
static const size_t O_FTBL = O_FTBH + 2097152;        // bf16 feat transposed lo
static const size_t O_WB   = O_FTBL + 2097152;        // bf16 weights: w11,w22,c1 (65536 each), c2 (131072)
static const size_t O_PT   = O_WB   + 163840;         // fp32 P/Q transposed [8][4096][256]
static const size_t O_RN   = O_PT   + 8388608;        // rnorm [4][4096]
static const size_t O_SS   = O_RN   + 16384;          // scale/shift: sc0,sh0,sc1,sh1 (256 ea), sc2,sh2 (512 ea)
static const size_t O_CB   = O_SS   + 2048;           // combined bias t11_b+t22_b+pos_b (256)  [R5: own slot]
static const size_t O_ST   = O_CB   + 256;            // stats 4 it * 128
static const size_t O_IDX  = O_ST   + 512;            // knn idx [4][4096][16]
static const size_t O_CAND = O_IDX  + 262144;         // candidates [4][4096][64]
static const size_t O_X0H  = O_CAND + 1048576;        // x0 hi bf16 [65536][256]
static const size_t O_X0L  = O_X0H  + 8388608;
static const size_t O_X1H  = O_X0L  + 8388608;
static const size_t O_X1L  = O_X1H  + 8388608;
static const size_t O_XMX  = O_X1L  + 8388608;        // [4096][512] fp32
static const size_t O_XMN  = O_XMX  + 2097152;

__device__ __forceinline__ ushort f2bf(float v) {
    uint u = __float_as_uint(v);
    return (ushort)((u + 0x7FFFu + ((u >> 16) & 1u)) >> 16);
}
__device__ __forceinline__ float bf2f(ushort u) {
    return __uint_as_float(((uint)u) << 16);
}

__global__ __launch_bounds__(256) void k_norms(const float* knn1, const float* knn2, float* rn) {
    int y = blockIdx.y;
    const float* src = (y >> 1) ? knn2 : knn1;
    src += (size_t)(y & 1) * NC * NPTS;
    int n = blockIdx.x * 256 + threadIdx.x;
    float ss = 0.f;
    for (int c = 0; c < NC; ++c) { float v = src[(size_t)c * NPTS + n]; ss = fmaf(v, v, ss); }
    rn[y * NPTS + n] = 1.f / fmaxf(sqrtf(ss), 1e-8f);
}

__global__ __launch_bounds__(256) void k_tr(const float* knn1, const float* knn2,
                                            const float* feat1, const float* feat2,
                                            float* ws) {
    __shared__ float t[64][65];
    int z = blockIdx.z;
    int isknn = (z < 4);
    int zz = isknn ? z : z - 4;
    int tnum = zz >> 1, b = zz & 1;
    const float* src = isknn ? (tnum ? knn2 : knn1) : (tnum ? feat2 : feat1);
    src += (size_t)b * NC * NPTS;
    const float* rn = ws + O_RN;
    int n0 = blockIdx.x * 64, c0 = blockIdx.y * 64;
    int cc = threadIdx.x & 63, rr = threadIdx.x >> 6;
#pragma unroll
    for (int i = 0; i < 16; ++i) {
        int r = rr + i * 4;
        t[r][cc] = src[(size_t)(c0 + r) * NPTS + n0 + cc];
    }
    __syncthreads();
    size_t base = (size_t)(tnum * 2 + b) * NPTS * NC;
    if (isknn) {
        float* ntf = ws + O_NTF + base;
        ushort* ntb = (ushort*)(ws + O_NTB) + base;
#pragma unroll
        for (int i = 0; i < 16; ++i) {
            int nr = rr + i * 4;
            float sc = rn[(tnum * 2 + b) * NPTS + n0 + nr];
            float v = t[cc][nr] * sc;
            ntf[(size_t)(n0 + nr) * NC + c0 + cc] = v;
            ntb[(size_t)(n0 + nr) * NC + c0 + cc] = f2bf(v);
        }
    } else {
        ushort* fh = (ushort*)(ws + O_FTBH) + base;
        ushort* fl = (ushort*)(ws + O_FTBL) + base;
#pragma unroll
        for (int i = 0; i < 16; ++i) {
            int nr = rr + i * 4;
            float v = t[cc][nr];
            ushort hh = f2bf(v);
            fh[(size_t)(n0 + nr) * NC + c0 + cc] = hh;
            fl[(size_t)(n0 + nr) * NC + c0 + cc] = f2bf(v - bf2f(hh));
        }
    }
}

__global__ __launch_bounds__(256) void k_wconv(const float* w11, const float* w22,
                                               const float* c1, const float* c2, ushort* wb) {
    int i = blockIdx.x * 256 + threadIdx.x;
    float v;
    if (i < 65536) v = w11[i];
    else if (i < 131072) v = w22[i - 65536];
    else if (i < 196608) v = c1[i - 131072];
    else v = c2[i - 196608];
    wb[i] = f2bf(v);
}

__global__ void k_cbias(const float* b1, const float* b2, const float* pb, float* cb) {
    int c = threadIdx.x;
    cb[c] = b1[c] + b2[c] + pb[c];
}

// ============ exact top-8 u64 helpers ============
__device__ __forceinline__ void topk_insert(ull* sl, ull& cm, float d, uint m) {
    ull cand = ((ull)__float_as_uint(d) << 32) | (ull)m;
    if (cand < cm) {
        bool done = false;
#pragma unroll
        for (int l = 0; l < 8; ++l) {
            bool rep = (!done) && (sl[l] == cm);
            if (rep) sl[l] = cand;
            done = done || rep;
        }
        cm = sl[0];
#pragma unroll
        for (int l = 1; l < 8; ++l) cm = (sl[l] > cm) ? sl[l] : cm;
    }
}

__device__ __forceinline__ void topk_merge(ull (&s8)[4][8], ull* mg, int* knn,
                                           size_t knnbase, int r0, int slot0, int tid) {
    int tx = tid & 31, ty = tid >> 5;
    for (int half = 0; half < 2; ++half) {
        __syncthreads();
        if ((ty >> 2) == half) {
#pragma unroll
            for (int i = 0; i < 4; ++i) {
                int ri = (ty & 3) * 4 + i;
#pragma unroll
                for (int l = 0; l < 8; ++l) mg[ri * 256 + tx * 8 + l] = s8[i][l];
            }
        }
        __syncthreads();
        int row16 = tid >> 4, sub = tid & 15;
        for (int round = 0; round < 8; ++round) {
            ull best = ~0ull; int bq = sub * 16;
#pragma unroll
            for (int q = 0; q < 16; ++q) {
                ull v = mg[row16 * 256 + sub * 16 + q];
                if (v < best) { best = v; bq = sub * 16 + q; }
            }
#pragma unroll
            for (int off = 8; off; off >>= 1) {
                ull ov = __shfl_down(best, off, 16);
                int oq = __shfl_down(bq, off, 16);
                if (ov < best) { best = ov; bq = oq; }
            }
            if (sub == 0) {
                mg[row16 * 256 + bq] = ~0ull;
                knn[knnbase + (size_t)(r0 + half * 16 + row16) * NS + slot0 + round] =
                    (int)(best & 0xFFFFFFFFull);
            }
            __syncthreads();
        }
    }
}

__global__ __launch_bounds__(256) void k_point_topk(const float* __restrict__ pc1, const float* __restrict__ pc2,
                                                    int* __restrict__ knn) {
    __shared__ ull smem[4096];
    float* smem_f = (float*)smem;
    ull*   mg  = smem;
    float* x1s = smem_f;
    float* x2s = smem_f + 96;

    int tid = threadIdx.x;
    int it = blockIdx.y;
    int dir = it >> 1, b = it & 1;
    const float* x1p = (dir ? pc2 : pc1) + (size_t)b * 3 * NPTS;
    const float* x2p = (dir ? pc1 : pc2) + (size_t)b * 3 * NPTS;
    size_t knnbase = (size_t)it * NPTS * NS;
    int r0 = blockIdx.x * 32;
    int tx = tid & 31, ty = tid >> 5;

    ull s8[4][8]; ull cmax[4];
#pragma unroll
    for (int i = 0; i < 4; ++i) { cmax[i] = ~0ull;
#pragma unroll
        for (int l = 0; l < 8; ++l) s8[i][l] = ~0ull; }

    if (tid < 96) { int aa = tid >> 5, r = tid & 31; x1s[aa * 32 + r] = x1p[(size_t)aa * NPTS + r0 + r]; }
    for (int ct = 0; ct < 32; ++ct) {
        __syncthreads();
#pragma unroll
        for (int q = 0; q < 2; ++q) {
            int flat = q * 256 + tid;
            if (flat < 384) {
                int aa = flat >> 7, col = flat & 127;
                x2s[aa * 128 + col] = x2p[(size_t)aa * NPTS + ct * 128 + col];
            }
        }
        __syncthreads();
#pragma unroll
        for (int ii = 0; ii < 4; ++ii) {
            float px = x1s[ty * 4 + ii], py = x1s[32 + ty * 4 + ii], pz = x1s[64 + ty * 4 + ii];
#pragma unroll
            for (int jj = 0; jj < 4; ++jj) {
                float dx = px - x2s[tx * 4 + jj];
                float dy = py - x2s[128 + tx * 4 + jj];
                float dz = pz - x2s[256 + tx * 4 + jj];
                float d = fmaf(dx, dx, fmaf(dy, dy, dz * dz));
                uint m = (uint)(ct * 128 + tx * 4 + jj);
                topk_insert(&s8[ii][0], cmax[ii], d, m);
            }
        }
    }
    topk_merge(s8, mg, knn, knnbase, r0, 0, tid);
}

__device__ __forceinline__ void ins8u32(uint* sl, uint& cm, uint cand) {
    if (cand < cm) {
        bool done = false;
#pragma unroll
        for (int l = 0; l < 8; ++l) {
            bool rep = (!done) && (sl[l] == cm);
            if (rep) sl[l] = cand;
            done = done || rep;
        }
        cm = sl[0];
#pragma unroll
        for (int l = 1; l < 8; ++l) cm = (sl[l] > cm) ? sl[l] : cm;
    }
}
__device__ __forceinline__ void ins16u32(uint* sl, uint& cm, uint cand) {
    if (cand < cm) {
        bool done = false;
#pragma unroll
        for (int l = 0; l < 16; ++l) {
            bool rep = (!done) && (sl[l] == cm);
            if (rep) sl[l] = cand;
            done = done || rep;
        }
        cm = sl[0];
#pragma unroll
        for (int l = 1; l < 16; ++l) cm = (sl[l] > cm) ? sl[l] : cm;
    }
}

__global__ __launch_bounds__(256) void k_feat(const ushort* __restrict__ ntb, uint* __restrict__ candb) {
    __shared__ uint mg[64 * 129];
    int tid = threadIdx.x;
    int it = blockIdx.z, dir = it >> 1, b = it & 1;
    const ushort* AT = ntb + (size_t)(dir * 2 + b) * NPTS * NC;
    const ushort* BT = ntb + (size_t)((1 - dir) * 2 + b) * NPTS * NC;
    int r0 = blockIdx.x * 64;
    int stripe = blockIdx.y;
    int w = tid >> 6, L = tid & 63, txm = L & 15, quad = L >> 4;

    short8 af[8];
    const ushort* arow = AT + (size_t)(r0 + w * 16 + txm) * NC + quad * 8;
#pragma unroll
    for (int ks = 0; ks < 8; ++ks) af[ks] = *(const short8*)(arow + ks * 32);

    uint list[4][8]; uint cm[4];
#pragma unroll
    for (int i = 0; i < 4; ++i) { cm[i] = 0xFFFFFFFFu;
#pragma unroll
        for (int l = 0; l < 8; ++l) list[i][l] = 0xFFFFFFFFu; }

#pragma unroll 1
    for (int jt = 0; jt < 16; ++jt) {
        int cb = stripe * 1024 + jt * 64;
        f32x4 acc[4];
#pragma unroll
        for (int s = 0; s < 4; ++s) acc[s] = (f32x4){0.f, 0.f, 0.f, 0.f};
        const ushort* bbase = BT + (size_t)(cb + txm) * NC + quad * 8;
#pragma unroll
        for (int ks = 0; ks < 8; ++ks) {
            short8 b0 = *(const short8*)(bbase + ks * 32);
            short8 b1 = *(const short8*)(bbase + (size_t)16 * NC + ks * 32);
            short8 b2 = *(const short8*)(bbase + (size_t)32 * NC + ks * 32);
            short8 b3 = *(const short8*)(bbase + (size_t)48 * NC + ks * 32);
            acc[0] = __builtin_amdgcn_mfma_f32_16x16x32_bf16(af[ks], b0, acc[0], 0, 0, 0);
            acc[1] = __builtin_amdgcn_mfma_f32_16x16x32_bf16(af[ks], b1, acc[1], 0, 0, 0);
            acc[2] = __builtin_amdgcn_mfma_f32_16x16x32_bf16(af[ks], b2, acc[2], 0, 0, 0);
            acc[3] = __builtin_amdgcn_mfma_f32_16x16x32_bf16(af[ks], b3, acc[3], 0, 0, 0);
        }
#pragma unroll
        for (int s = 0; s < 4; ++s) {
            uint colb = (uint)(jt * 64 + s * 16 + txm);
#pragma unroll
            for (int reg = 0; reg < 4; ++reg) {
                float d = fmaxf(1.0f - acc[s][reg], 0.0f);
                uint cd = (__float_as_uint(d) & 0xFFFFF000u) | colb;
                ins8u32(list[reg], cm[reg], cd);
            }
        }
    }
    __syncthreads();
#pragma unroll
    for (int reg = 0; reg < 4; ++reg) {
        int row = w * 16 + quad * 4 + reg;
#pragma unroll
        for (int l = 0; l < 8; ++l) mg[row * 129 + txm * 8 + l] = list[reg][l];
    }
    __syncthreads();
    if (tid < 128) {
        int row = tid >> 1, half = tid & 1;
        uint best[16]; uint bcm = 0xFFFFFFFFu;
#pragma unroll
        for (int l = 0; l < 16; ++l) best[l] = 0xFFFFFFFFu;
        const uint* src = &mg[row * 129 + half * 64];
        for (int i = 0; i < 64; ++i) ins16u32(best, bcm, src[i]);
        uint* dstp = &mg[row * 129 + half * 64];
#pragma unroll
        for (int l = 0; l < 16; ++l) dstp[l] = best[l];
    }
    __syncthreads();
    if (tid < 64) {
        uint best[16]; uint bcm = 0xFFFFFFFFu;
#pragma unroll
        for (int l = 0; l < 16; ++l) best[l] = 0xFFFFFFFFu;
        const uint* s0 = &mg[tid * 129];
        for (int i = 0; i < 16; ++i) ins16u32(best, bcm, s0[i]);
        const uint* s1 = &mg[tid * 129 + 64];
        for (int i = 0; i < 16; ++i) ins16u32(best, bcm, s1[i]);
        uint* dst = candb + ((size_t)it * NPTS + r0 + tid) * 64 + stripe * 16;
#pragma unroll
        for (int l = 0; l < 16; ++l) dst[l] = (best[l] & 0xFFFu) + stripe * 1024;
    }
}

__device__ __forceinline__ void ins8u64(ull* sl, ull& cm, ull cand) {
    if (cand < cm) {
        bool done = false;
#pragma unroll
        for (int l = 0; l < 8; ++l) {
            bool rep = (!done) && (sl[l] == cm);
            if (rep) sl[l] = cand;
            done = done || rep;
        }
        cm = sl[0];
#pragma unroll
        for (int l = 1; l < 8; ++l) cm = (sl[l] > cm) ? sl[l] : cm;
    }
}

__global__ __launch_bounds__(256) void k_rescore(const float* __restrict__ ntf,
                                                 const uint* __restrict__ candb,
                                                 int* __restrict__ knn) {
    int it = blockIdx.y, dir = it >> 1, b = it & 1;
    const float* AT = ntf + (size_t)(dir * 2 + b) * NPTS * NC;
    const float* BT = ntf + (size_t)((1 - dir) * 2 + b) * NPTS * NC;
    int w = threadIdx.x >> 6, L = threadIdx.x & 63;
    int r = blockIdx.x * 4 + w;
    const uint* cand = candb + ((size_t)it * NPTS + r) * 64;
    float4 a = *(const float4*)(AT + (size_t)r * NC + L * 4);
    ull sl[8]; ull cm = ~0ull;
#pragma unroll
    for (int l = 0; l < 8; ++l) sl[l] = ~0ull;
#pragma unroll 1
    for (int c = 0; c < 64; ++c) {
        uint col = cand[c];
        float4 bb = *(const float4*)(BT + (size_t)col * NC + L * 4);
        float p = a.x * bb.x;
        p = fmaf(a.y, bb.y, p); p = fmaf(a.z, bb.z, p); p = fmaf(a.w, bb.w, p);
#pragma unroll
        for (int off = 32; off; off >>= 1) p += __shfl_xor(p, off);
        float d = 1.0f - p;
        uint u = __float_as_uint(d);
        uint key = u ^ ((uint)((int)u >> 31) | 0x80000000u);
        ins8u64(sl, cm, ((ull)key << 32) | (ull)col);
    }
    for (int s = 0; s < 8; ++s) {
        ull bv = sl[0];
#pragma unroll
        for (int c = 1; c < 8; ++c) bv = (sl[c] < bv) ? sl[c] : bv;
        if (L == 0)
            knn[(size_t)it * NPTS * NS + (size_t)r * NS + 8 + s] = (int)(uint)(bv & 0xFFFFull);
#pragma unroll
        for (int c = 0; c < 8; ++c) sl[c] = (sl[c] == bv) ? ~0ull : sl[c];
    }
}

// ============ unified split-A MFMA matmul: D[j][o] = sum_c (Ah+Al)[j][c] * W[o][c] ============
__global__ __launch_bounds__(256) void k_mm(const ushort* __restrict__ Ahb, const ushort* __restrict__ Alb,
                                            const ushort* __restrict__ Wbase,
                                            const float* __restrict__ obias,
                                            float* __restrict__ stats, float* __restrict__ out32,
                                            ushort* __restrict__ outh, ushort* __restrict__ outl,
                                            float* __restrict__ xmaxT, float* __restrict__ xminT,
                                            int mode) {
    __shared__ ushort wlds[64 * 264];
    int tid = threadIdx.x;
    int w = tid >> 6, L = tid & 63, txm = L & 15, quad = L >> 4;
    int o0 = blockIdx.x * 64;
    int j0 = blockIdx.y * 64;
    const ushort* Ah = Ahb; const ushort* Al = Alb;
    const ushort* Wp = Wbase; float* o32 = out32;
    if (mode == 0) {
        int z = blockIdx.z, q = z >> 1, b = z & 1;
        int t = (q == 1 || q == 2) ? 1 : 0;
        size_t off = (size_t)(t * 2 + b) * NPTS * NC;
        Ah = Ahb + off; Al = Alb + off;
        Wp = Wbase + ((q & 1) ? 65536 : 0);
        o32 = out32 + ((size_t)(q * 2 + b)) * NPTS * NC;
    }
    {
        int row = tid >> 2, part = tid & 3;
        const uint4* src = (const uint4*)(Wp + (size_t)(o0 + row) * NC + part * 64);
        uint4* dst = (uint4*)(wlds + row * 264 + part * 64);
#pragma unroll
        for (int i = 0; i < 8; ++i) dst[i] = src[i];
    }
    __syncthreads();
    f32x4 acc[4];
#pragma unroll
    for (int s = 0; s < 4; ++s) acc[s] = (f32x4){0.f, 0.f, 0.f, 0.f};
    const ushort* arh = Ah + (size_t)(j0 + w * 16 + txm) * NC + quad * 8;
    const ushort* arl = Al + (size_t)(j0 + w * 16 + txm) * NC + quad * 8;
#pragma unroll
    for (int ks = 0; ks < 8; ++ks) {
        short8 ah = *(const short8*)(arh + ks * 32);
        short8 al = *(const short8*)(arl + ks * 32);
#pragma unroll
        for (int s = 0; s < 4; ++s) {
            short8 wf = *(const short8*)(wlds + (s * 16 + txm) * 264 + ks * 32 + quad * 8);
            acc[s] = __builtin_amdgcn_mfma_f32_16x16x32_bf16(al, wf, acc[s], 0, 0, 0);
            acc[s] = __builtin_amdgcn_mfma_f32_16x16x32_bf16(ah, wf, acc[s], 0, 0, 0);
        }
    }
    if (mode == 0) {
#pragma unroll
        for (int s = 0; s < 4; ++s)
#pragma unroll
            for (int reg = 0; reg < 4; ++reg) {
                int n = j0 + w * 16 + quad * 4 + reg;
                o32[(size_t)n * NC + o0 + s * 16 + txm] = acc[s][reg];
            }
        return;
    }
    int gn = (j0 + w * 16) >> 4;
#pragma unroll
    for (int s = 0; s < 4; ++s) {
        float bb = obias[o0 + s * 16 + txm];
#pragma unroll
        for (int reg = 0; reg < 4; ++reg) acc[s][reg] += bb;
        float p1 = acc[s][0] + acc[s][1] + acc[s][2] + acc[s][3];
        float p2 = acc[s][0] * acc[s][0] + acc[s][1] * acc[s][1]
                 + acc[s][2] * acc[s][2] + acc[s][3] * acc[s][3];
#pragma unroll
        for (int off = 32; off; off >>= 1) { p1 += __shfl_down(p1, off); p2 += __shfl_down(p2, off); }
        if (L == 0) {
            int g = (o0 >> 4) + s;
            unsafeAtomicAdd(&stats[2 * g], p1);
            unsafeAtomicAdd(&stats[2 * g + 1], p2);
        }
        if (mode == 1) {
#pragma unroll
            for (int reg = 0; reg < 4; ++reg) {
                int j = j0 + w * 16 + quad * 4 + reg;
                float v = acc[s][reg];
                ushort hh = f2bf(v);
                outh[(size_t)j * NC + o0 + s * 16 + txm] = hh;
                outl[(size_t)j * NC + o0 + s * 16 + txm] = f2bf(v - bf2f(hh));
            }
        } else {
            float mx = fmaxf(fmaxf(acc[s][0], acc[s][1]), fmaxf(acc[s][2], acc[s][3]));
            float mn = fminf(fminf(acc[s][0], acc[s][1]), fminf(acc[s][2], acc[s][3]));
            mx = fmaxf(mx, __shfl_xor(mx, 16)); mx = fmaxf(mx, __shfl_xor(mx, 32));
            mn = fminf(mn, __shfl_xor(mn, 16)); mn = fminf(mn, __shfl_xor(mn, 32));
            if (L < 16) {
                xmaxT[(size_t)gn * M2C + o0 + s * 16 + L] = mx;
                xminT[(size_t)gn * M2C + o0 + s * 16 + L] = mn;
            }
        }
    }
}

// ============ in-place activation: x <- split(leaky(sc*x + sh)) ============
__global__ __launch_bounds__(256) void k_act(ushort* __restrict__ xh, ushort* __restrict__ xl,
                                             const float* __restrict__ sc, const float* __restrict__ sh) {
    size_t base = ((size_t)blockIdx.x * 256 + threadIdx.x) * 8;
    int c0 = (int)(base & 255);
    uint4 h4 = *(uint4*)(xh + base);
    uint4 l4 = *(uint4*)(xl + base);
    float4 sA = *(const float4*)(sc + c0), sB = *(const float4*)(sc + c0 + 4);
    float4 hA = *(const float4*)(sh + c0), hB = *(const float4*)(sh + c0 + 4);
    float sv[8] = {sA.x, sA.y, sA.z, sA.w, sB.x, sB.y, sB.z, sB.w};
    float tv[8] = {hA.x, hA.y, hA.z, hA.w, hB.x, hB.y, hB.z, hB.w};
    uint hv[4] = {h4.x, h4.y, h4.z, h4.w};
    uint lv[4] = {l4.x, l4.y, l4.z, l4.w};
    uint oh[4], ol[4];
#pragma unroll
    for (int i = 0; i < 4; ++i) {
        float f0 = bf2f((ushort)(hv[i] & 0xFFFFu)) + bf2f((ushort)(lv[i] & 0xFFFFu));
        float f1 = bf2f((ushort)(hv[i] >> 16)) + bf2f((ushort)(lv[i] >> 16));
        f0 = fmaf(f0, sv[2 * i], tv[2 * i]);     f0 = fmaxf(f0, SLOPE * f0);
        f1 = fmaf(f1, sv[2 * i + 1], tv[2 * i + 1]); f1 = fmaxf(f1, SLOPE * f1);
        ushort h0 = f2bf(f0), h1 = f2bf(f1);
        ushort l0 = f2bf(f0 - bf2f(h0)), l1 = f2bf(f1 - bf2f(h1));
        oh[i] = (uint)h0 | ((uint)h1 << 16);
        ol[i] = (uint)l0 | ((uint)l1 << 16);
    }
    *(uint4*)(xh + base) = (uint4){oh[0], oh[1], oh[2], oh[3]};
    *(uint4*)(xl + base) = (uint4){ol[0], ol[1], ol[2], ol[3]};
}

// ============ build x0 split = P2t[m]+P1t[n]+pos·dxyz+cbias ; gn0 stats ============
__global__ __launch_bounds__(256) void k_build_x0(const float* __restrict__ P1t, const float* __restrict__ P2t,
                                                  const float* __restrict__ xyz1, const float* __restrict__ xyz2,
                                                  const int* __restrict__ idx,
                                                  const float* __restrict__ pos_w, const float* __restrict__ cbias,
                                                  ushort* __restrict__ x0h, ushort* __restrict__ x0l,
                                                  float* __restrict__ stats) {
    __shared__ float sg[32];
    int tid = threadIdx.x;
    if (tid < 32) sg[tid] = 0.f;
    __syncthreads();
    int cpart = tid & 15, c0 = cpart * 16;
    int jl = tid >> 4;
    float pwf[48], pbf[16];
    {
        const float4* pv = (const float4*)(pos_w + c0 * 3);
#pragma unroll
        for (int i = 0; i < 12; ++i) {
            float4 v = pv[i];
            pwf[i * 4 + 0] = v.x; pwf[i * 4 + 1] = v.y; pwf[i * 4 + 2] = v.z; pwf[i * 4 + 3] = v.w;
        }
        const float4* pb = (const float4*)(cbias + c0);
#pragma unroll
        for (int i = 0; i < 4; ++i) {
            float4 v = pb[i];
            pbf[i * 4 + 0] = v.x; pbf[i * 4 + 1] = v.y; pbf[i * 4 + 2] = v.z; pbf[i * 4 + 3] = v.w;
        }
    }
    float s1 = 0.f, s2 = 0.f;
#pragma unroll
    for (int jj = 0; jj < 4; ++jj) {
        int j = blockIdx.x * 64 + jl * 4 + jj;
        int n = j >> 4;
        int m = idx[j];
        float dx = xyz2[m] - xyz1[n];
        float dy = xyz2[NPTS + m] - xyz1[NPTS + n];
        float dz = xyz2[2 * NPTS + m] - xyz1[2 * NPTS + n];
        const float4* p2 = (const float4*)(P2t + (size_t)m * NC + c0);
        const float4* p1 = (const float4*)(P1t + (size_t)n * NC + c0);
        uint oh[8], ol[8];
#pragma unroll
        for (int q = 0; q < 4; ++q) {
            float4 a = p2[q], bb = p1[q];
            float e0 = a.x + bb.x, e1 = a.y + bb.y, e2 = a.z + bb.z, e3 = a.w + bb.w;
            int ci = q * 4;
            e0 = fmaf(pwf[ci * 3 + 0], dx, e0); e0 = fmaf(pwf[ci * 3 + 1], dy, e0); e0 = fmaf(pwf[ci * 3 + 2], dz, e0); e0 += pbf[ci];
            e1 = fmaf(pwf[ci * 3 + 3], dx, e1); e1 = fmaf(pwf[ci * 3 + 4], dy, e1); e1 = fmaf(pwf[ci * 3 + 5], dz, e1); e1 += pbf[ci + 1];
            e2 = fmaf(pwf[ci * 3 + 6], dx, e2); e2 = fmaf(pwf[ci * 3 + 7], dy, e2); e2 = fmaf(pwf[ci * 3 + 8], dz, e2); e2 += pbf[ci + 2];
            e3 = fmaf(pwf[ci * 3 + 9], dx, e3); e3 = fmaf(pwf[ci * 3 + 10], dy, e3); e3 = fmaf(pwf[ci * 3 + 11], dz, e3); e3 += pbf[ci + 3];
            s1 += e0 + e1 + e2 + e3;
            s2 = fmaf(e0, e0, s2); s2 = fmaf(e1, e1, s2); s2 = fmaf(e2, e2, s2); s2 = fmaf(e3, e3, s2);
            ushort h0 = f2bf(e0), h1 = f2bf(e1), h2 = f2bf(e2), h3 = f2bf(e3);
            oh[q * 2]     = (uint)h0 | ((uint)h1 << 16);
            oh[q * 2 + 1] = (uint)h2 | ((uint)h3 << 16);
            ol[q * 2]     = (uint)f2bf(e0 - bf2f(h0)) | ((uint)f2bf(e1 - bf2f(h1)) << 16);
            ol[q * 2 + 1] = (uint)f2bf(e2 - bf2f(h2)) | ((uint)f2bf(e3 - bf2f(h3)) << 16);
        }
        uint4* dh = (uint4*)(x0h + (size_t)j * NC + c0);
        dh[0] = ((uint4*)oh)[0]; dh[1] = ((uint4*)oh)[1];
        uint4* dl = (uint4*)(x0l + (size_t)j * NC + c0);
        dl[0] = ((uint4*)ol)[0]; dl[1] = ((uint4*)ol)[1];
    }
    atomicAdd(&sg[2 * cpart], s1);
    atomicAdd(&sg[2 * cpart + 1], s2);
    __syncthreads();
    if (tid < 32) unsafeAtomicAdd(&stats[tid], sg[tid]);
}

__global__ void k_finalize(const float* __restrict__ stats, const float* __restrict__ gamma,
                           const float* __restrict__ beta, float* __restrict__ sc,
                           float* __restrict__ sh, int Cn) {
    int c = blockIdx.x * 256 + threadIdx.x;
    if (c >= Cn) return;
    int g = c >> 4;
    const float inv = 1.0f / 1048576.0f;
    float mean = stats[2 * g] * inv;
    float var = stats[2 * g + 1] * inv - mean * mean;
    float rs = rsqrtf(var + GEPS);
    float s = gamma[c] * rs;
    sc[c] = s;
    sh[c] = beta[c] - mean * s;
}

__global__ __launch_bounds__(256) void k_out(const float* __restrict__ xmx, const float* __restrict__ xmn,
                                             const float* __restrict__ sc, const float* __restrict__ sh,
                                             float* __restrict__ outp) {
    __shared__ float t[64][65];
    int n0 = blockIdx.x * 64, o0 = blockIdx.y * 64;
    int cc = threadIdx.x & 63, rr = threadIdx.x >> 6;
    int o = o0 + cc;
    float s = sc[o], h = sh[o];
    const float* srcm = (s >= 0.f) ? xmx : xmn;
#pragma unroll
    for (int i = 0; i < 16; ++i) {
        int nr = rr + i * 4;
        float v = srcm[(size_t)(n0 + nr) * M2C + o];
        v = fmaf(v, s, h);
        v = fmaxf(v, SLOPE * v);
        t[nr][cc] = v;
    }
    __syncthreads();
#pragma unroll
    for (int i = 0; i < 16; ++i) {
        int orr = rr + i * 4;
        outp[(size_t)(o0 + orr) * NPTS + n0 + cc] = t[cc][orr];
    }
}

extern "C" void kernel_launch(void* const* d_in, const int* in_sizes, int n_in,
                              void* d_out, int out_size, void* d_ws, size_t ws_size,
                              hipStream_t stream) {
    const float* pc1   = (const float*)d_in[0];
    const float* pc2   = (const float*)d_in[1];
    const float* feat1 = (const float*)d_in[2];
    const float* feat2 = (const float*)d_in[3];
    const float* knn1  = (const float*)d_in[4];
    const float* knn2  = (const float*)d_in[5];
    const float* t11_w = (const float*)d_in[6];
    const float* t11_b = (const float*)d_in[7];
    const float* t22_w = (const float*)d_in[8];
    const float* t22_b = (const float*)d_in[9];
    const float* pos_w = (const float*)d_in[10];
    const float* pos_b = (const float*)d_in[11];
    const float* gn0_w = (const float*)d_in[12];
    const float* gn0_b = (const float*)d_in[13];
    const float* c1_w  = (const float*)d_in[14];
    const float* c1_b  = (const float*)d_in[15];
    const float* gn1_w = (const float*)d_in[16];
    const float* gn1_b = (const float*)d_in[17];
    const float* c2_w  = (const float*)d_in[18];
    const float* c2_b  = (const float*)d_in[19];
    const float* gn2_w = (const float*)d_in[20];
    const float* gn2_b = (const float*)d_in[21];
    float* ws = (float*)d_ws;
    float* outp = (float*)d_out;

    ushort* WB   = (ushort*)(ws + O_WB);
    ushort* NTB  = (ushort*)(ws + O_NTB);
    ushort* FTBH = (ushort*)(ws + O_FTBH);
    ushort* FTBL = (ushort*)(ws + O_FTBL);
    ushort* X0H  = (ushort*)(ws + O_X0H);
    ushort* X0L  = (ushort*)(ws + O_X0L);
    ushort* X1H  = (ushort*)(ws + O_X1H);
    ushort* X1L  = (ushort*)(ws + O_X1L);
    int* IDX = (int*)(ws + O_IDX);
    uint* CAND = (uint*)(ws + O_CAND);

    hipMemsetAsync(ws + O_ST, 0, 512 * sizeof(float), stream);
    k_norms<<<dim3(16, 4), 256, 0, stream>>>(knn1, knn2, ws + O_RN);
    k_tr<<<dim3(64, 4, 8), 256, 0, stream>>>(knn1, knn2, feat1, feat2, ws);
    k_wconv<<<dim3(1280), 256, 0, stream>>>(t11_w, t22_w, c1_w, c2_w, WB);
    k_cbias<<<dim3(1), 256, 0, stream>>>(t11_b, t22_b, pos_b, ws + O_CB);
    k_point_topk<<<dim3(128, 4), 256, 0, stream>>>(pc1, pc2, IDX);
    k_feat<<<dim3(64, 4, 4), 256, 0, stream>>>(NTB, CAND);
    k_rescore<<<dim3(1024, 4), 256, 0, stream>>>(ws + O_NTF, CAND, IDX);

    // pq convs: P/Q transposed fp32 (split-A from feat)
    k_mm<<<dim3(4, 64, 8), 256, 0, stream>>>(FTBH, FTBL, WB, nullptr, nullptr,
                                             ws + O_PT, nullptr, nullptr, nullptr, nullptr, 0);

    float* sc0 = ws + O_SS; float* sh0 = sc0 + 256;
    float* sc1 = sc0 + 512; float* sh1 = sc0 + 768;
    float* sc2 = sc0 + 1024; float* sh2 = sc0 + 1536;
    float* CB = ws + O_CB;

    for (int itx = 0; itx < 4; ++itx) {
        int dir = itx >> 1, b = itx & 1;
        const float* P1t = ws + O_PT + (size_t)((dir ? 2 : 0) * 2 + b) * NPTS * NC;
        const float* P2t = ws + O_PT + (size_t)((dir ? 3 : 1) * 2 + b) * NPTS * NC;
        const float* xyz1 = (dir ? pc2 : pc1) + (size_t)b * 3 * NPTS;
        const float* xyz2 = (dir ? pc1 : pc2) + (size_t)b * 3 * NPTS;
        const int* idx = IDX + (size_t)itx * NPTS * NS;
        float* st = ws + O_ST + itx * 128;

        k_build_x0<<<dim3(1024), 256, 0, stream>>>(P1t, P2t, xyz1, xyz2, idx, pos_w, CB,
                                                   X0H, X0L, st);
        k_finalize<<<dim3(1), 256, 0, stream>>>(st, gn0_w, gn0_b, sc0, sh0, 256);
        k_act<<<dim3(8192), 256, 0, stream>>>(X0H, X0L, sc0, sh0);
        k_mm<<<dim3(4, 1024), 256, 0, stream>>>(X0H, X0L, WB + 131072, c1_b, st + 32,
                                                nullptr, X1H, X1L, nullptr, nullptr, 1);
        k_finalize<<<dim3(1), 256, 0, stream>>>(st + 32, gn1_w, gn1_b, sc1, sh1, 256);
        k_act<<<dim3(8192), 256, 0, stream>>>(X1H, X1L, sc1, sh1);
        k_mm<<<dim3(8, 1024), 256, 0, stream>>>(X1H, X1L, WB + 196608, c2_b, st + 64,
                                                nullptr, nullptr, nullptr, ws + O_XMX, ws + O_XMN, 2);
        k_finalize<<<dim3(2), 256, 0, stream>>>(st + 64, gn2_w, gn2_b, sc2, sh2, 512);
        k_out<<<dim3(64, 8), 256, 0, stream>>>(ws + O_XMX, ws + O_XMN, sc2, sh2,
                                               outp + (size_t)itx * M2C * NPTS);
    }
}

// Round 6
// 2318.978 us; speedup vs baseline: 5.6620x; 5.6620x over previous
//
#include <hip/hip_runtime.h>
#include <stdint.h>

typedef unsigned long long ull;
typedef unsigned int uint;
typedef unsigned short ushort;

#define NPTS 4096
#define NC   256
#define M2C  512
#define NS   16
#define SLOPE 0.1f
#define GEPS 1e-5f

typedef __attribute__((ext_vector_type(8))) short short8;
typedef __attribute__((ext_vector_type(4))) float f32x4;

// ---- workspace layout (float units) ----
static const size_t O_NTF  = 0;                       // fp32 normalized knn, transposed [4][4096][256]
static const size_t O_NTB  = O_NTF  + 4194304;        // bf16 same
static const size_t O_FTBH = O_NTB  + 2097152;        // bf16 feat transposed hi [4][4096][256]
static const size_t O_FTBL = O_FTBH + 2097152;        // bf16 feat transposed lo
static const size_t O_WB   = O_FTBL + 2097152;        // bf16 weights: w11,w22,c1 (65536 ea), c2 (131072)
static const size_t O_PT   = O_WB   + 163840;         // fp32 P/Q transposed [8][4096][256]
static const size_t O_RN   = O_PT   + 8388608;        // rnorm [4][4096]
static const size_t O_SS   = O_RN   + 16384;          // scale/shift: sc0,sh0,sc1,sh1,sc2,sh2
static const size_t O_CB   = O_SS   + 2048;           // combined bias (256)
static const size_t O_PS   = O_CB   + 256;            // stat partials [1024][64]
static const size_t O_IDX  = O_PS   + 65536;          // knn idx [4][4096][16]
static const size_t O_CAND = O_IDX  + 262144;         // candidates [4][4096][64]
static const size_t O_X0H  = O_CAND + 1048576;        // x0 hi bf16 [65536][256]
static const size_t O_X0L  = O_X0H  + 8388608;
static const size_t O_X1H  = O_X0L  + 8388608;
static const size_t O_X1L  = O_X1H  + 8388608;
static const size_t O_XMX  = O_X1L  + 8388608;        // [4096][512] fp32
static const size_t O_XMN  = O_XMX  + 2097152;

__device__ __forceinline__ ushort f2bf(float v) {
    uint u = __float_as_uint(v);
    return (ushort)((u + 0x7FFFu + ((u >> 16) & 1u)) >> 16);
}
__device__ __forceinline__ float bf2f(ushort u) {
    return __uint_as_float(((uint)u) << 16);
}

__global__ __launch_bounds__(256) void k_norms(const float* knn1, const float* knn2, float* rn) {
    int y = blockIdx.y;
    const float* src = (y >> 1) ? knn2 : knn1;
    src += (size_t)(y & 1) * NC * NPTS;
    int n = blockIdx.x * 256 + threadIdx.x;
    float ss = 0.f;
    for (int c = 0; c < NC; ++c) { float v = src[(size_t)c * NPTS + n]; ss = fmaf(v, v, ss); }
    rn[y * NPTS + n] = 1.f / fmaxf(sqrtf(ss), 1e-8f);
}

__global__ __launch_bounds__(256) void k_tr(const float* knn1, const float* knn2,
                                            const float* feat1, const float* feat2,
                                            float* ws) {
    __shared__ float t[64][65];
    int z = blockIdx.z;
    int isknn = (z < 4);
    int zz = isknn ? z : z - 4;
    int tnum = zz >> 1, b = zz & 1;
    const float* src = isknn ? (tnum ? knn2 : knn1) : (tnum ? feat2 : feat1);
    src += (size_t)b * NC * NPTS;
    const float* rn = ws + O_RN;
    int n0 = blockIdx.x * 64, c0 = blockIdx.y * 64;
    int cc = threadIdx.x & 63, rr = threadIdx.x >> 6;
#pragma unroll
    for (int i = 0; i < 16; ++i) {
        int r = rr + i * 4;
        t[r][cc] = src[(size_t)(c0 + r) * NPTS + n0 + cc];
    }
    __syncthreads();
    size_t base = (size_t)(tnum * 2 + b) * NPTS * NC;
    if (isknn) {
        float* ntf = ws + O_NTF + base;
        ushort* ntb = (ushort*)(ws + O_NTB) + base;
#pragma unroll
        for (int i = 0; i < 16; ++i) {
            int nr = rr + i * 4;
            float sc = rn[(tnum * 2 + b) * NPTS + n0 + nr];
            float v = t[cc][nr] * sc;
            ntf[(size_t)(n0 + nr) * NC + c0 + cc] = v;
            ntb[(size_t)(n0 + nr) * NC + c0 + cc] = f2bf(v);
        }
    } else {
        ushort* fh = (ushort*)(ws + O_FTBH) + base;
        ushort* fl = (ushort*)(ws + O_FTBL) + base;
#pragma unroll
        for (int i = 0; i < 16; ++i) {
            int nr = rr + i * 4;
            float v = t[cc][nr];
            ushort hh = f2bf(v);
            fh[(size_t)(n0 + nr) * NC + c0 + cc] = hh;
            fl[(size_t)(n0 + nr) * NC + c0 + cc] = f2bf(v - bf2f(hh));
        }
    }
}

__global__ __launch_bounds__(256) void k_wconv(const float* w11, const float* w22,
                                               const float* c1, const float* c2, ushort* wb) {
    int i = blockIdx.x * 256 + threadIdx.x;
    float v;
    if (i < 65536) v = w11[i];
    else if (i < 131072) v = w22[i - 65536];
    else if (i < 196608) v = c1[i - 131072];
    else v = c2[i - 196608];
    wb[i] = f2bf(v);
}

__global__ void k_cbias(const float* b1, const float* b2, const float* pb, float* cb) {
    int c = threadIdx.x;
    cb[c] = b1[c] + b2[c] + pb[c];
}

// ============ exact top-8 u64 helpers ============
__device__ __forceinline__ void topk_insert(ull* sl, ull& cm, float d, uint m) {
    ull cand = ((ull)__float_as_uint(d) << 32) | (ull)m;
    if (cand < cm) {
        bool done = false;
#pragma unroll
        for (int l = 0; l < 8; ++l) {
            bool rep = (!done) && (sl[l] == cm);
            if (rep) sl[l] = cand;
            done = done || rep;
        }
        cm = sl[0];
#pragma unroll
        for (int l = 1; l < 8; ++l) cm = (sl[l] > cm) ? sl[l] : cm;
    }
}

__device__ __forceinline__ void topk_merge(ull (&s8)[4][8], ull* mg, int* knn,
                                           size_t knnbase, int r0, int slot0, int tid) {
    int tx = tid & 31, ty = tid >> 5;
    for (int half = 0; half < 2; ++half) {
        __syncthreads();
        if ((ty >> 2) == half) {
#pragma unroll
            for (int i = 0; i < 4; ++i) {
                int ri = (ty & 3) * 4 + i;
#pragma unroll
                for (int l = 0; l < 8; ++l) mg[ri * 256 + tx * 8 + l] = s8[i][l];
            }
        }
        __syncthreads();
        int row16 = tid >> 4, sub = tid & 15;
        for (int round = 0; round < 8; ++round) {
            ull best = ~0ull; int bq = sub * 16;
#pragma unroll
            for (int q = 0; q < 16; ++q) {
                ull v = mg[row16 * 256 + sub * 16 + q];
                if (v < best) { best = v; bq = sub * 16 + q; }
            }
#pragma unroll
            for (int off = 8; off; off >>= 1) {
                ull ov = __shfl_down(best, off, 16);
                int oq = __shfl_down(bq, off, 16);
                if (ov < best) { best = ov; bq = oq; }
            }
            if (sub == 0) {
                mg[row16 * 256 + bq] = ~0ull;
                knn[knnbase + (size_t)(r0 + half * 16 + row16) * NS + slot0 + round] =
                    (int)(best & 0xFFFFFFFFull);
            }
            __syncthreads();
        }
    }
}

__global__ __launch_bounds__(256) void k_point_topk(const float* __restrict__ pc1, const float* __restrict__ pc2,
                                                    int* __restrict__ knn) {
    __shared__ ull smem[4096];
    float* smem_f = (float*)smem;
    ull*   mg  = smem;
    float* x1s = smem_f;
    float* x2s = smem_f + 96;

    int tid = threadIdx.x;
    int it = blockIdx.y;
    int dir = it >> 1, b = it & 1;
    const float* x1p = (dir ? pc2 : pc1) + (size_t)b * 3 * NPTS;
    const float* x2p = (dir ? pc1 : pc2) + (size_t)b * 3 * NPTS;
    size_t knnbase = (size_t)it * NPTS * NS;
    int r0 = blockIdx.x * 32;
    int tx = tid & 31, ty = tid >> 5;

    ull s8[4][8]; ull cmax[4];
#pragma unroll
    for (int i = 0; i < 4; ++i) { cmax[i] = ~0ull;
#pragma unroll
        for (int l = 0; l < 8; ++l) s8[i][l] = ~0ull; }

    if (tid < 96) { int aa = tid >> 5, r = tid & 31; x1s[aa * 32 + r] = x1p[(size_t)aa * NPTS + r0 + r]; }
    for (int ct = 0; ct < 32; ++ct) {
        __syncthreads();
#pragma unroll
        for (int q = 0; q < 2; ++q) {
            int flat = q * 256 + tid;
            if (flat < 384) {
                int aa = flat >> 7, col = flat & 127;
                x2s[aa * 128 + col] = x2p[(size_t)aa * NPTS + ct * 128 + col];
            }
        }
        __syncthreads();
#pragma unroll
        for (int ii = 0; ii < 4; ++ii) {
            float px = x1s[ty * 4 + ii], py = x1s[32 + ty * 4 + ii], pz = x1s[64 + ty * 4 + ii];
#pragma unroll
            for (int jj = 0; jj < 4; ++jj) {
                float dx = px - x2s[tx * 4 + jj];
                float dy = py - x2s[128 + tx * 4 + jj];
                float dz = pz - x2s[256 + tx * 4 + jj];
                float d = fmaf(dx, dx, fmaf(dy, dy, dz * dz));
                uint m = (uint)(ct * 128 + tx * 4 + jj);
                topk_insert(&s8[ii][0], cmax[ii], d, m);
            }
        }
    }
    topk_merge(s8, mg, knn, knnbase, r0, 0, tid);
}

__device__ __forceinline__ void ins8u32(uint* sl, uint& cm, uint cand) {
    if (cand < cm) {
        bool done = false;
#pragma unroll
        for (int l = 0; l < 8; ++l) {
            bool rep = (!done) && (sl[l] == cm);
            if (rep) sl[l] = cand;
            done = done || rep;
        }
        cm = sl[0];
#pragma unroll
        for (int l = 1; l < 8; ++l) cm = (sl[l] > cm) ? sl[l] : cm;
    }
}
__device__ __forceinline__ void ins16u32(uint* sl, uint& cm, uint cand) {
    if (cand < cm) {
        bool done = false;
#pragma unroll
        for (int l = 0; l < 16; ++l) {
            bool rep = (!done) && (sl[l] == cm);
            if (rep) sl[l] = cand;
            done = done || rep;
        }
        cm = sl[0];
#pragma unroll
        for (int l = 1; l < 16; ++l) cm = (sl[l] > cm) ? sl[l] : cm;
    }
}

__global__ __launch_bounds__(256) void k_feat(const ushort* __restrict__ ntb, uint* __restrict__ candb) {
    __shared__ uint mg[64 * 129];
    int tid = threadIdx.x;
    int it = blockIdx.z, dir = it >> 1, b = it & 1;
    const ushort* AT = ntb + (size_t)(dir * 2 + b) * NPTS * NC;
    const ushort* BT = ntb + (size_t)((1 - dir) * 2 + b) * NPTS * NC;
    int r0 = blockIdx.x * 64;
    int stripe = blockIdx.y;
    int w = tid >> 6, L = tid & 63, txm = L & 15, quad = L >> 4;

    short8 af[8];
    const ushort* arow = AT + (size_t)(r0 + w * 16 + txm) * NC + quad * 8;
#pragma unroll
    for (int ks = 0; ks < 8; ++ks) af[ks] = *(const short8*)(arow + ks * 32);

    uint list[4][8]; uint cm[4];
#pragma unroll
    for (int i = 0; i < 4; ++i) { cm[i] = 0xFFFFFFFFu;
#pragma unroll
        for (int l = 0; l < 8; ++l) list[i][l] = 0xFFFFFFFFu; }

#pragma unroll 1
    for (int jt = 0; jt < 16; ++jt) {
        int cb = stripe * 1024 + jt * 64;
        f32x4 acc[4];
#pragma unroll
        for (int s = 0; s < 4; ++s) acc[s] = (f32x4){0.f, 0.f, 0.f, 0.f};
        const ushort* bbase = BT + (size_t)(cb + txm) * NC + quad * 8;
#pragma unroll
        for (int ks = 0; ks < 8; ++ks) {
            short8 b0 = *(const short8*)(bbase + ks * 32);
            short8 b1 = *(const short8*)(bbase + (size_t)16 * NC + ks * 32);
            short8 b2 = *(const short8*)(bbase + (size_t)32 * NC + ks * 32);
            short8 b3 = *(const short8*)(bbase + (size_t)48 * NC + ks * 32);
            acc[0] = __builtin_amdgcn_mfma_f32_16x16x32_bf16(af[ks], b0, acc[0], 0, 0, 0);
            acc[1] = __builtin_amdgcn_mfma_f32_16x16x32_bf16(af[ks], b1, acc[1], 0, 0, 0);
            acc[2] = __builtin_amdgcn_mfma_f32_16x16x32_bf16(af[ks], b2, acc[2], 0, 0, 0);
            acc[3] = __builtin_amdgcn_mfma_f32_16x16x32_bf16(af[ks], b3, acc[3], 0, 0, 0);
        }
#pragma unroll
        for (int s = 0; s < 4; ++s) {
            uint colb = (uint)(jt * 64 + s * 16 + txm);
#pragma unroll
            for (int reg = 0; reg < 4; ++reg) {
                float d = fmaxf(1.0f - acc[s][reg], 0.0f);
                uint cd = (__float_as_uint(d) & 0xFFFFF000u) | colb;
                ins8u32(list[reg], cm[reg], cd);
            }
        }
    }
    __syncthreads();
#pragma unroll
    for (int reg = 0; reg < 4; ++reg) {
        int row = w * 16 + quad * 4 + reg;
#pragma unroll
        for (int l = 0; l < 8; ++l) mg[row * 129 + txm * 8 + l] = list[reg][l];
    }
    __syncthreads();
    if (tid < 128) {
        int row = tid >> 1, half = tid & 1;
        uint best[16]; uint bcm = 0xFFFFFFFFu;
#pragma unroll
        for (int l = 0; l < 16; ++l) best[l] = 0xFFFFFFFFu;
        const uint* src = &mg[row * 129 + half * 64];
        for (int i = 0; i < 64; ++i) ins16u32(best, bcm, src[i]);
        uint* dstp = &mg[row * 129 + half * 64];
#pragma unroll
        for (int l = 0; l < 16; ++l) dstp[l] = best[l];
    }
    __syncthreads();
    if (tid < 64) {
        uint best[16]; uint bcm = 0xFFFFFFFFu;
#pragma unroll
        for (int l = 0; l < 16; ++l) best[l] = 0xFFFFFFFFu;
        const uint* s0 = &mg[tid * 129];
        for (int i = 0; i < 16; ++i) ins16u32(best, bcm, s0[i]);
        const uint* s1 = &mg[tid * 129 + 64];
        for (int i = 0; i < 16; ++i) ins16u32(best, bcm, s1[i]);
        uint* dst = candb + ((size_t)it * NPTS + r0 + tid) * 64 + stripe * 16;
#pragma unroll
        for (int l = 0; l < 16; ++l) dst[l] = (best[l] & 0xFFFu) + stripe * 1024;
    }
}

__device__ __forceinline__ void ins8u64(ull* sl, ull& cm, ull cand) {
    if (cand < cm) {
        bool done = false;
#pragma unroll
        for (int l = 0; l < 8; ++l) {
            bool rep = (!done) && (sl[l] == cm);
            if (rep) sl[l] = cand;
            done = done || rep;
        }
        cm = sl[0];
#pragma unroll
        for (int l = 1; l < 8; ++l) cm = (sl[l] > cm) ? sl[l] : cm;
    }
}

__global__ __launch_bounds__(256) void k_rescore(const float* __restrict__ ntf,
                                                 const uint* __restrict__ candb,
                                                 int* __restrict__ knn) {
    int it = blockIdx.y, dir = it >> 1, b = it & 1;
    const float* AT = ntf + (size_t)(dir * 2 + b) * NPTS * NC;
    const float* BT = ntf + (size_t)((1 - dir) * 2 + b) * NPTS * NC;
    int w = threadIdx.x >> 6, L = threadIdx.x & 63;
    int r = blockIdx.x * 4 + w;
    const uint* cand = candb + ((size_t)it * NPTS + r) * 64;
    float4 a = *(const float4*)(AT + (size_t)r * NC + L * 4);
    ull sl[8]; ull cm = ~0ull;
#pragma unroll
    for (int l = 0; l < 8; ++l) sl[l] = ~0ull;
#pragma unroll 1
    for (int c = 0; c < 64; ++c) {
        uint col = cand[c];
        float4 bb = *(const float4*)(BT + (size_t)col * NC + L * 4);
        float p = a.x * bb.x;
        p = fmaf(a.y, bb.y, p); p = fmaf(a.z, bb.z, p); p = fmaf(a.w, bb.w, p);
#pragma unroll
        for (int off = 32; off; off >>= 1) p += __shfl_xor(p, off);
        float d = 1.0f - p;
        uint u = __float_as_uint(d);
        uint key = u ^ ((uint)((int)u >> 31) | 0x80000000u);
        ins8u64(sl, cm, ((ull)key << 32) | (ull)col);
    }
    for (int s = 0; s < 8; ++s) {
        ull bv = sl[0];
#pragma unroll
        for (int c = 1; c < 8; ++c) bv = (sl[c] < bv) ? sl[c] : bv;
        if (L == 0)
            knn[(size_t)it * NPTS * NS + (size_t)r * NS + 8 + s] = (int)(uint)(bv & 0xFFFFull);
#pragma unroll
        for (int c = 0; c < 8; ++c) sl[c] = (sl[c] == bv) ? ~0ull : sl[c];
    }
}

// ============ restructured split-A MFMA matmul ============
// Grid = j-tiles only; block computes ALL O columns looping o-chunks of 64.
// A (hi+lo, 8 ks frags) loaded once into regs, optional fused GN-affine+leaky.
// W fragments read directly from global (L2-resident). GN stats -> per-block
// partials in pstat[block][64] (no global atomics).
// mode 0: pq conv (fp32 out, blockIdx.y selects combo); mode 1: conv1 (split
// bf16 out + bias + stats); mode 2: conv2 (bias + stats + max/min per n).
__global__ __launch_bounds__(256, 3) void k_mm(const ushort* __restrict__ Ahb, const ushort* __restrict__ Alb,
                                               const ushort* __restrict__ Wbase,
                                               const float* __restrict__ obias,
                                               const float* __restrict__ ssc, const float* __restrict__ ssh,
                                               float* __restrict__ pstat, float* __restrict__ out32,
                                               ushort* __restrict__ outh, ushort* __restrict__ outl,
                                               float* __restrict__ xmaxT, float* __restrict__ xminT,
                                               int mode, int O) {
    __shared__ float sgrp[64];
    int tid = threadIdx.x;
    int w = tid >> 6, L = tid & 63, txm = L & 15, quad = L >> 4;
    int j0 = blockIdx.x * 64;
    const ushort* Ah = Ahb; const ushort* Al = Alb;
    const ushort* Wp = Wbase; float* o32 = out32;
    if (mode == 0) {
        int z = blockIdx.y, q = z >> 1, b = z & 1;
        int t = (q == 1 || q == 2) ? 1 : 0;
        size_t off = (size_t)(t * 2 + b) * NPTS * NC;
        Ah = Ahb + off; Al = Alb + off;
        Wp = Wbase + ((q & 1) ? 65536 : 0);
        o32 = out32 + ((size_t)(q * 2 + b)) * NPTS * NC;
    }
    // load all A fragments (8 ks, hi+lo), fused act if ssc
    const ushort* arh = Ah + (size_t)(j0 + w * 16 + txm) * NC + quad * 8;
    const ushort* arl = Al + (size_t)(j0 + w * 16 + txm) * NC + quad * 8;
    short8 ah[8], al[8];
#pragma unroll
    for (int ks = 0; ks < 8; ++ks) {
        ah[ks] = *(const short8*)(arh + ks * 32);
        al[ks] = *(const short8*)(arl + ks * 32);
    }
    if (mode != 0) {
#pragma unroll
        for (int ks = 0; ks < 8; ++ks) {
            int cb = ks * 32 + quad * 8;
            float4 s1 = *(const float4*)(ssc + cb), s2 = *(const float4*)(ssc + cb + 4);
            float4 h1 = *(const float4*)(ssh + cb), h2 = *(const float4*)(ssh + cb + 4);
            float sa[8] = {s1.x, s1.y, s1.z, s1.w, s2.x, s2.y, s2.z, s2.w};
            float ha[8] = {h1.x, h1.y, h1.z, h1.w, h2.x, h2.y, h2.z, h2.w};
#pragma unroll
            for (int i = 0; i < 8; ++i) {
                float f = bf2f((ushort)ah[ks][i]) + bf2f((ushort)al[ks][i]);
                f = fmaf(f, sa[i], ha[i]);
                f = fmaxf(f, SLOPE * f);
                ushort hh = f2bf(f);
                ah[ks][i] = (short)hh;
                al[ks][i] = (short)f2bf(f - bf2f(hh));
            }
        }
        if (tid < 64) sgrp[tid] = 0.f;
        __syncthreads();
    }
    int nchunk = O >> 6;
    int gn = (j0 + w * 16) >> 4;
#pragma unroll 1
    for (int oc = 0; oc < nchunk; ++oc) {
        int o0 = oc * 64;
        f32x4 acc[4];
#pragma unroll
        for (int s = 0; s < 4; ++s) acc[s] = (f32x4){0.f, 0.f, 0.f, 0.f};
#pragma unroll
        for (int ks = 0; ks < 8; ++ks) {
#pragma unroll
            for (int s = 0; s < 4; ++s) {
                short8 wf = *(const short8*)(Wp + (size_t)(o0 + s * 16 + txm) * NC + ks * 32 + quad * 8);
                acc[s] = __builtin_amdgcn_mfma_f32_16x16x32_bf16(al[ks], wf, acc[s], 0, 0, 0);
                acc[s] = __builtin_amdgcn_mfma_f32_16x16x32_bf16(ah[ks], wf, acc[s], 0, 0, 0);
            }
        }
        if (mode == 0) {
#pragma unroll
            for (int s = 0; s < 4; ++s)
#pragma unroll
                for (int reg = 0; reg < 4; ++reg) {
                    int n = j0 + w * 16 + quad * 4 + reg;
                    o32[(size_t)n * NC + o0 + s * 16 + txm] = acc[s][reg];
                }
            continue;
        }
#pragma unroll
        for (int s = 0; s < 4; ++s) {
            int col = o0 + s * 16 + txm;
            float bb = obias[col];
#pragma unroll
            for (int reg = 0; reg < 4; ++reg) acc[s][reg] += bb;
            float p1 = acc[s][0] + acc[s][1] + acc[s][2] + acc[s][3];
            float p2 = acc[s][0] * acc[s][0] + acc[s][1] * acc[s][1]
                     + acc[s][2] * acc[s][2] + acc[s][3] * acc[s][3];
#pragma unroll
            for (int off = 32; off; off >>= 1) { p1 += __shfl_down(p1, off); p2 += __shfl_down(p2, off); }
            if (L == 0) {
                int g = oc * 4 + s;
                atomicAdd(&sgrp[2 * g], p1);
                atomicAdd(&sgrp[2 * g + 1], p2);
            }
            if (mode == 1) {
#pragma unroll
                for (int reg = 0; reg < 4; ++reg) {
                    int j = j0 + w * 16 + quad * 4 + reg;
                    float v = acc[s][reg];
                    ushort hh = f2bf(v);
                    outh[(size_t)j * NC + col] = hh;
                    outl[(size_t)j * NC + col] = f2bf(v - bf2f(hh));
                }
            } else {
                float mx = fmaxf(fmaxf(acc[s][0], acc[s][1]), fmaxf(acc[s][2], acc[s][3]));
                float mn = fminf(fminf(acc[s][0], acc[s][1]), fminf(acc[s][2], acc[s][3]));
                mx = fmaxf(mx, __shfl_xor(mx, 16)); mx = fmaxf(mx, __shfl_xor(mx, 32));
                mn = fminf(mn, __shfl_xor(mn, 16)); mn = fminf(mn, __shfl_xor(mn, 32));
                if (L < 16) {
                    xmaxT[(size_t)gn * M2C + o0 + s * 16 + L] = mx;
                    xminT[(size_t)gn * M2C + o0 + s * 16 + L] = mn;
                }
            }
        }
    }
    if (mode != 0) {
        __syncthreads();
        if (tid < 64) pstat[(size_t)blockIdx.x * 64 + tid] = sgrp[tid];
    }
}

// ============ build x0 split = P2t[m]+P1t[n]+pos·dxyz+cbias ; gn0 stat partials ============
__global__ __launch_bounds__(256) void k_build_x0(const float* __restrict__ P1t, const float* __restrict__ P2t,
                                                  const float* __restrict__ xyz1, const float* __restrict__ xyz2,
                                                  const int* __restrict__ idx,
                                                  const float* __restrict__ pos_w, const float* __restrict__ cbias,
                                                  ushort* __restrict__ x0h, ushort* __restrict__ x0l,
                                                  float* __restrict__ pstat) {
    __shared__ float sg[32];
    int tid = threadIdx.x;
    if (tid < 32) sg[tid] = 0.f;
    __syncthreads();
    int cpart = tid & 15, c0 = cpart * 16;
    int jl = tid >> 4;
    float pwf[48], pbf[16];
    {
        const float4* pv = (const float4*)(pos_w + c0 * 3);
#pragma unroll
        for (int i = 0; i < 12; ++i) {
            float4 v = pv[i];
            pwf[i * 4 + 0] = v.x; pwf[i * 4 + 1] = v.y; pwf[i * 4 + 2] = v.z; pwf[i * 4 + 3] = v.w;
        }
        const float4* pb = (const float4*)(cbias + c0);
#pragma unroll
        for (int i = 0; i < 4; ++i) {
            float4 v = pb[i];
            pbf[i * 4 + 0] = v.x; pbf[i * 4 + 1] = v.y; pbf[i * 4 + 2] = v.z; pbf[i * 4 + 3] = v.w;
        }
    }
    float s1 = 0.f, s2 = 0.f;
#pragma unroll
    for (int jj = 0; jj < 4; ++jj) {
        int j = blockIdx.x * 64 + jl * 4 + jj;
        int n = j >> 4;
        int m = idx[j];
        float dx = xyz2[m] - xyz1[n];
        float dy = xyz2[NPTS + m] - xyz1[NPTS + n];
        float dz = xyz2[2 * NPTS + m] - xyz1[2 * NPTS + n];
        const float4* p2 = (const float4*)(P2t + (size_t)m * NC + c0);
        const float4* p1 = (const float4*)(P1t + (size_t)n * NC + c0);
        uint oh[8], ol[8];
#pragma unroll
        for (int q = 0; q < 4; ++q) {
            float4 a = p2[q], bb = p1[q];
            float e0 = a.x + bb.x, e1 = a.y + bb.y, e2 = a.z + bb.z, e3 = a.w + bb.w;
            int ci = q * 4;
            e0 = fmaf(pwf[ci * 3 + 0], dx, e0); e0 = fmaf(pwf[ci * 3 + 1], dy, e0); e0 = fmaf(pwf[ci * 3 + 2], dz, e0); e0 += pbf[ci];
            e1 = fmaf(pwf[ci * 3 + 3], dx, e1); e1 = fmaf(pwf[ci * 3 + 4], dy, e1); e1 = fmaf(pwf[ci * 3 + 5], dz, e1); e1 += pbf[ci + 1];
            e2 = fmaf(pwf[ci * 3 + 6], dx, e2); e2 = fmaf(pwf[ci * 3 + 7], dy, e2); e2 = fmaf(pwf[ci * 3 + 8], dz, e2); e2 += pbf[ci + 2];
            e3 = fmaf(pwf[ci * 3 + 9], dx, e3); e3 = fmaf(pwf[ci * 3 + 10], dy, e3); e3 = fmaf(pwf[ci * 3 + 11], dz, e3); e3 += pbf[ci + 3];
            s1 += e0 + e1 + e2 + e3;
            s2 = fmaf(e0, e0, s2); s2 = fmaf(e1, e1, s2); s2 = fmaf(e2, e2, s2); s2 = fmaf(e3, e3, s2);
            ushort h0 = f2bf(e0), h1 = f2bf(e1), h2 = f2bf(e2), h3 = f2bf(e3);
            oh[q * 2]     = (uint)h0 | ((uint)h1 << 16);
            oh[q * 2 + 1] = (uint)h2 | ((uint)h3 << 16);
            ol[q * 2]     = (uint)f2bf(e0 - bf2f(h0)) | ((uint)f2bf(e1 - bf2f(h1)) << 16);
            ol[q * 2 + 1] = (uint)f2bf(e2 - bf2f(h2)) | ((uint)f2bf(e3 - bf2f(h3)) << 16);
        }
        uint4* dh = (uint4*)(x0h + (size_t)j * NC + c0);
        dh[0] = ((uint4*)oh)[0]; dh[1] = ((uint4*)oh)[1];
        uint4* dl = (uint4*)(x0l + (size_t)j * NC + c0);
        dl[0] = ((uint4*)ol)[0]; dl[1] = ((uint4*)ol)[1];
    }
    atomicAdd(&sg[2 * cpart], s1);
    atomicAdd(&sg[2 * cpart + 1], s2);
    __syncthreads();
    if (tid < 32) pstat[(size_t)blockIdx.x * 64 + tid] = sg[tid];
}

// ============ sum stat partials [1024][64] -> scale/shift ============
__global__ __launch_bounds__(256) void k_finalize2(const float* __restrict__ pstat,
                                                   const float* __restrict__ gamma,
                                                   const float* __restrict__ beta,
                                                   float* __restrict__ sc, float* __restrict__ sh,
                                                   int Cn) {
    __shared__ float ps[4][64];
    __shared__ float gsum[64];
    int tid = threadIdx.x;
    int t = tid & 63, part = tid >> 6;
    float s = 0.f;
    for (int i = part * 256; i < part * 256 + 256; ++i) s += pstat[(size_t)i * 64 + t];
    ps[part][t] = s;
    __syncthreads();
    if (tid < 64) gsum[tid] = ps[0][tid] + ps[1][tid] + ps[2][tid] + ps[3][tid];
    __syncthreads();
    const float inv = 1.0f / 1048576.0f;
    for (int c = tid; c < Cn; c += 256) {
        int g = c >> 4;
        float mean = gsum[2 * g] * inv;
        float var = gsum[2 * g + 1] * inv - mean * mean;
        float rs = rsqrtf(var + GEPS);
        float scale = gamma[c] * rs;
        sc[c] = scale;
        sh[c] = beta[c] - mean * scale;
    }
}

__global__ __launch_bounds__(256) void k_out(const float* __restrict__ xmx, const float* __restrict__ xmn,
                                             const float* __restrict__ sc, const float* __restrict__ sh,
                                             float* __restrict__ outp) {
    __shared__ float t[64][65];
    int n0 = blockIdx.x * 64, o0 = blockIdx.y * 64;
    int cc = threadIdx.x & 63, rr = threadIdx.x >> 6;
    int o = o0 + cc;
    float s = sc[o], h = sh[o];
    const float* srcm = (s >= 0.f) ? xmx : xmn;
#pragma unroll
    for (int i = 0; i < 16; ++i) {
        int nr = rr + i * 4;
        float v = srcm[(size_t)(n0 + nr) * M2C + o];
        v = fmaf(v, s, h);
        v = fmaxf(v, SLOPE * v);
        t[nr][cc] = v;
    }
    __syncthreads();
#pragma unroll
    for (int i = 0; i < 16; ++i) {
        int orr = rr + i * 4;
        outp[(size_t)(o0 + orr) * NPTS + n0 + cc] = t[cc][orr];
    }
}

extern "C" void kernel_launch(void* const* d_in, const int* in_sizes, int n_in,
                              void* d_out, int out_size, void* d_ws, size_t ws_size,
                              hipStream_t stream) {
    const float* pc1   = (const float*)d_in[0];
    const float* pc2   = (const float*)d_in[1];
    const float* feat1 = (const float*)d_in[2];
    const float* feat2 = (const float*)d_in[3];
    const float* knn1  = (const float*)d_in[4];
    const float* knn2  = (const float*)d_in[5];
    const float* t11_w = (const float*)d_in[6];
    const float* t11_b = (const float*)d_in[7];
    const float* t22_w = (const float*)d_in[8];
    const float* t22_b = (const float*)d_in[9];
    const float* pos_w = (const float*)d_in[10];
    const float* pos_b = (const float*)d_in[11];
    const float* gn0_w = (const float*)d_in[12];
    const float* gn0_b = (const float*)d_in[13];
    const float* c1_w  = (const float*)d_in[14];
    const float* c1_b  = (const float*)d_in[15];
    const float* gn1_w = (const float*)d_in[16];
    const float* gn1_b = (const float*)d_in[17];
    const float* c2_w  = (const float*)d_in[18];
    const float* c2_b  = (const float*)d_in[19];
    const float* gn2_w = (const float*)d_in[20];
    const float* gn2_b = (const float*)d_in[21];
    float* ws = (float*)d_ws;
    float* outp = (float*)d_out;

    ushort* WB   = (ushort*)(ws + O_WB);
    ushort* NTB  = (ushort*)(ws + O_NTB);
    ushort* FTBH = (ushort*)(ws + O_FTBH);
    ushort* FTBL = (ushort*)(ws + O_FTBL);
    ushort* X0H  = (ushort*)(ws + O_X0H);
    ushort* X0L  = (ushort*)(ws + O_X0L);
    ushort* X1H  = (ushort*)(ws + O_X1H);
    ushort* X1L  = (ushort*)(ws + O_X1L);
    int* IDX = (int*)(ws + O_IDX);
    uint* CAND = (uint*)(ws + O_CAND);
    float* PS = ws + O_PS;

    k_norms<<<dim3(16, 4), 256, 0, stream>>>(knn1, knn2, ws + O_RN);
    k_tr<<<dim3(64, 4, 8), 256, 0, stream>>>(knn1, knn2, feat1, feat2, ws);
    k_wconv<<<dim3(1280), 256, 0, stream>>>(t11_w, t22_w, c1_w, c2_w, WB);
    k_cbias<<<dim3(1), 256, 0, stream>>>(t11_b, t22_b, pos_b, ws + O_CB);
    k_point_topk<<<dim3(128, 4), 256, 0, stream>>>(pc1, pc2, IDX);
    k_feat<<<dim3(64, 4, 4), 256, 0, stream>>>(NTB, CAND);
    k_rescore<<<dim3(1024, 4), 256, 0, stream>>>(ws + O_NTF, CAND, IDX);

    // pq convs: P/Q transposed fp32 (split-A from feat), all-O per block
    k_mm<<<dim3(64, 8), 256, 0, stream>>>(FTBH, FTBL, WB, nullptr, nullptr, nullptr,
                                          nullptr, ws + O_PT, nullptr, nullptr,
                                          nullptr, nullptr, 0, 256);

    float* sc0 = ws + O_SS; float* sh0 = sc0 + 256;
    float* sc1 = sc0 + 512; float* sh1 = sc0 + 768;
    float* sc2 = sc0 + 1024; float* sh2 = sc0 + 1536;
    float* CB = ws + O_CB;

    for (int itx = 0; itx < 4; ++itx) {
        int dir = itx >> 1, b = itx & 1;
        const float* P1t = ws + O_PT + (size_t)((dir ? 2 : 0) * 2 + b) * NPTS * NC;
        const float* P2t = ws + O_PT + (size_t)((dir ? 3 : 1) * 2 + b) * NPTS * NC;
        const float* xyz1 = (dir ? pc2 : pc1) + (size_t)b * 3 * NPTS;
        const float* xyz2 = (dir ? pc1 : pc2) + (size_t)b * 3 * NPTS;
        const int* idx = IDX + (size_t)itx * NPTS * NS;

        k_build_x0<<<dim3(1024), 256, 0, stream>>>(P1t, P2t, xyz1, xyz2, idx, pos_w, CB,
                                                   X0H, X0L, PS);
        k_finalize2<<<dim3(1), 256, 0, stream>>>(PS, gn0_w, gn0_b, sc0, sh0, 256);
        k_mm<<<dim3(1024), 256, 0, stream>>>(X0H, X0L, WB + 131072, c1_b, sc0, sh0,
                                             PS, nullptr, X1H, X1L, nullptr, nullptr, 1, 256);
        k_finalize2<<<dim3(1), 256, 0, stream>>>(PS, gn1_w, gn1_b, sc1, sh1, 256);
        k_mm<<<dim3(1024), 256, 0, stream>>>(X1H, X1L, WB + 196608, c2_b, sc1, sh1,
                                             PS, nullptr, nullptr, nullptr,
                                             ws + O_XMX, ws + O_XMN, 2, 512);
        k_finalize2<<<dim3(2), 256, 0, stream>>>(PS, gn2_w, gn2_b, sc2, sh2, 512);
        k_out<<<dim3(64, 8), 256, 0, stream>>>(ws + O_XMX, ws + O_XMN, sc2, sh2,
                                               outp + (size_t)itx * M2C * NPTS);
    }
}